// Round 2
// baseline (560.538 us; speedup 1.0000x reference)
//
#include <hip/hip_runtime.h>

// ---------------------------------------------------------------------------
// SelfAttentionModule: q/k/v proj + relative_key_query attention, MI355X.
// B=4, S=1024, D=1024, H=16, HD=64, MAXPOS=1024.
//
//   k_detect    : runtime input-dtype sniff (bf16 vs f32) -> flags[0]
//   k_prep      : normalize hidden/dist_emb -> bf16 ws; mask/bias/hm -> f32 ws
//   k_transpose : W[k][n] -> Wt[n][k] bf16
//   k_qkv_gemm  : 128x128 MFMA tile GEMM; writes q,k row-major [bh][s][d],
//                 v TRANSPOSED [bh][d][s] (so k_attn needs no LDS transpose)
//   k_attn      : fused attention, 48 KB LDS (3 blocks/CU), XOR-swizzled
//                 tiles, Q-frags from global, Dq via ds_bpermute (no LDS),
//                 Dk via packed b64 col-major board, 3 barriers/iter.
// ---------------------------------------------------------------------------

typedef unsigned short u16;
typedef unsigned int   u32;
typedef unsigned long long u64;
typedef __attribute__((ext_vector_type(8))) short bfx8;   // 8 bf16 = 4 VGPR
typedef __attribute__((ext_vector_type(4))) float f32x4;  // MFMA C/D

#define MFMA_BF16(a, b, c) __builtin_amdgcn_mfma_f32_16x16x32_bf16(a, b, c, 0, 0, 0)

__device__ __forceinline__ u16 f2bf(float f) {
    union { float f; u32 u; } c; c.f = f;
    u32 u = c.u;
    return (u16)((u + 0x7FFFu + ((u >> 16) & 1u)) >> 16);  // RNE
}
__device__ __forceinline__ float bf2f(u16 v) {
    union { u32 u; float f; } c; c.u = ((u32)v) << 16;
    return c.f;
}
__device__ __forceinline__ float load_f(const void* p, long i, bool bf) {
    return bf ? bf2f(((const u16*)p)[i]) : ((const float*)p)[i];
}
__device__ __forceinline__ u16 load_bf(const void* p, long i, bool bf) {
    return bf ? ((const u16*)p)[i] : f2bf(((const float*)p)[i]);
}

// async global->LDS, 16B/lane; LDS dest = wave-uniform base + lane*16
__device__ __forceinline__ void gload16(const u16* g, u16* l) {
    __builtin_amdgcn_global_load_lds(
        (__attribute__((address_space(1))) void*)g,
        (__attribute__((address_space(3))) void*)l, 16, 0, 0);
}

// swizzled b128 read: row pitch 64 u16 (128B = 8 chunks of 16B), chunk XOR row
__device__ __forceinline__ bfx8 ld_sw(const u16* arr, int row, int chunk) {
    return *(const bfx8*)(arr + row * 64 + ((chunk ^ (row & 7)) * 8));
}

// ---------------------------------------------------------------------------
__global__ void k_detect(const u32* hid, int* flags) {
    __shared__ int cnt;
    if (threadIdx.x == 0) cnt = 0;
    __syncthreads();
    int c = 0;
    for (int i = threadIdx.x; i < 1024; i += 256) {
        u32 w = hid[i];
        u32 e = (w >> 7) & 0xFFu;
        if (e >= 100u && e <= 140u) c++;
    }
    atomicAdd(&cnt, c);
    __syncthreads();
    if (threadIdx.x == 0) flags[0] = (cnt > 512) ? 1 : 0;
}

// ---------------------------------------------------------------------------
__global__ void k_prep(const void* hidden, const void* dist, const void* mask,
                       const void* hm, const void* bq, const void* bk,
                       const void* bv, const int* flags, u16* hid_bf,
                       u16* dist_bf, float* mask_f, float* hm_f, float* bias_f) {
    const bool bf = flags[0] != 0;
    const long NH = 4L * 1024 * 1024, ND = 2047L * 64, NM = 4096, NB = 3072, NHM = 16;
    const long TOT = NH + ND + NM + NB + NHM;
    for (long i = (long)blockIdx.x * 256 + threadIdx.x; i < TOT;
         i += (long)gridDim.x * 256) {
        if (i < NH) hid_bf[i] = load_bf(hidden, i, bf);
        else if (i < NH + ND) dist_bf[i - NH] = load_bf(dist, i - NH, bf);
        else if (i < NH + ND + NM) mask_f[i - NH - ND] = load_f(mask, i - NH - ND, bf);
        else if (i < NH + ND + NM + NB) {
            long j = i - NH - ND - NM;
            const void* src = (j < 1024) ? bq : ((j < 2048) ? bk : bv);
            bias_f[j] = load_f(src, j & 1023, bf);
        } else {
            long j = i - NH - ND - NM - NB;
            hm_f[j] = load_f(hm, j, bf);
        }
    }
}

// W[k][n] -> Wt[n][k] (bf16). grid (32,32,3), block (32,8)
__global__ void k_transpose(const void* Wq, const void* Wk, const void* Wv,
                            const int* flags, u16* wt) {
    const bool bf = flags[0] != 0;
    __shared__ float t[32][33];
    const int z = blockIdx.z;
    const void* W = (z == 0) ? Wq : ((z == 1) ? Wk : Wv);
    int x = blockIdx.x * 32 + threadIdx.x;  // n
    for (int i = 0; i < 4; i++) {
        int y = blockIdx.y * 32 + threadIdx.y + i * 8;  // k
        t[threadIdx.y + i * 8][threadIdx.x] = load_f(W, (long)y * 1024 + x, bf);
    }
    __syncthreads();
    int x2 = blockIdx.y * 32 + threadIdx.x;  // k
    u16* out = wt + (long)z * 1024 * 1024;
    for (int i = 0; i < 4; i++) {
        int y2 = blockIdx.x * 32 + threadIdx.y + i * 8;  // n
        out[(long)y2 * 1024 + x2] = f2bf(t[threadIdx.x][threadIdx.y + i * 8]);
    }
}

// ---------------------------------------------------------------------------
// QKV GEMM: C[m,n] = sum_k A[m,k]*Wt[n,k] + bias[n]; M=4096, N=3072, K=1024.
__global__ __launch_bounds__(256, 2)
void k_qkv_gemm(const u16* A, const u16* Bt, const float* bias,
                u16* qb, u16* kb, u16* vb) {
    __shared__ u16 sA[128 * 32];  // unpadded: required by global_load_lds
    __shared__ u16 sB[128 * 32];
    const int tid = threadIdx.x;
    const int w = tid >> 6, lane = tid & 63;
    const int quad = lane >> 4, nl = lane & 15;
    const int wr = w >> 1, wc = w & 1;
    const int n0 = blockIdx.x * 128, m0 = blockIdx.y * 128;

    f32x4 acc[4][4];
#pragma unroll
    for (int a = 0; a < 4; a++)
#pragma unroll
        for (int b = 0; b < 4; b++) acc[a][b] = (f32x4){0.f, 0.f, 0.f, 0.f};

    for (int kt = 0; kt < 32; kt++) {
        const int k0 = kt * 32;
        __syncthreads();
#pragma unroll
        for (int j = 0; j < 2; j++) {
            int row = 32 * w + 16 * j + (lane >> 2);
            int seg = lane & 3;
            gload16(A + (long)(m0 + row) * 1024 + k0 + seg * 8, sA + 1024 * w + 512 * j);
            gload16(Bt + (long)(n0 + row) * 1024 + k0 + seg * 8, sB + 1024 * w + 512 * j);
        }
        __syncthreads();

        bfx8 af[4], bfr[4];
#pragma unroll
        for (int f = 0; f < 4; f++) {
            af[f]  = *(const bfx8*)(sA + (64 * wr + 16 * f + nl) * 32 + quad * 8);
            bfr[f] = *(const bfx8*)(sB + (64 * wc + 16 * f + nl) * 32 + quad * 8);
        }
#pragma unroll
        for (int fm = 0; fm < 4; fm++)
#pragma unroll
            for (int fn = 0; fn < 4; fn++)
                acc[fm][fn] = MFMA_BF16(af[fm], bfr[fn], acc[fm][fn]);
    }

    // epilogue: +bias; q,k -> [bh][s][64]; v -> TRANSPOSED [bh][64][s]
#pragma unroll
    for (int fm = 0; fm < 4; fm++) {
#pragma unroll
        for (int fn = 0; fn < 4; fn++) {
            int n = n0 + 64 * wc + 16 * fn + nl;
            int which = n >> 10, hcol = n & 1023;
            int h = hcol >> 6, hd = hcol & 63;
            float bias_v = bias[n];
            int mbase = m0 + 64 * wr + 16 * fm + 4 * quad;
            int b = mbase >> 10, s = mbase & 1023;  // 4-reg group same row b
            if (which == 2) {
                u64 pk = 0;
#pragma unroll
                for (int reg = 0; reg < 4; reg++)
                    pk |= (u64)f2bf(acc[fm][fn][reg] + bias_v) << (16 * reg);
                *(u64*)&vb[((long)((b * 16 + h) * 64 + hd)) * 1024 + s] = pk;
            } else {
                u16* op = (which == 0) ? qb : kb;
#pragma unroll
                for (int reg = 0; reg < 4; reg++)
                    op[((long)((b * 16 + h) * 1024 + s + reg)) * 64 + hd] =
                        f2bf(acc[fm][fn][reg] + bias_v);
            }
        }
    }
}

// ---------------------------------------------------------------------------
// Fused attention. grid (B*H=64, S/64=16), 256 threads = 4 waves.
// Wave w owns score rows 16w..16w+15 of the 64-row l-tile.
// LDS 48 KB -> 3 blocks/CU. All tiles XOR-swizzled (16B chunks), unpadded.
__global__ __launch_bounds__(256, 3)
void k_attn(const u16* qb, const u16* kb, const u16* vTb, const u16* Eb,
            const float* maskf, const float* hmf, const void* prior,
            const int* flags, void* out) {
    __shared__ __align__(16) u16 smem[24576];  // 49152 B
    u16* sK  = smem;           // [64 r][64 d]   swizzled
    u16* sVT = smem + 4096;    // [64 d][64 r]   swizzled
    u16* sE  = smem + 8192;    // [128 j][64 d]  swizzled
    u16* sP  = smem + 8192;    // aliases low half of sE (E dead by then)
    u16* sDk = smem + 16384;   // [128 u][64 r]  col-major, 8B-chunk swizzle

    const int tid = threadIdx.x;
    const int w = tid >> 6, lane = tid & 63;
    const int quad = lane >> 4, nl = lane & 15;
    const int rloc = lane >> 3;                   // row-within-8 for staging
    const int cperm = (lane & 7) ^ rloc;          // global chunk permutation
    const int bh = blockIdx.x, b = bh >> 4, h = bh & 15;
    const int l0 = blockIdx.y * 64;
    const bool bf = flags[0] != 0;

    const u16* qbh = qb  + (long)bh * 65536;
    const u16* kbh = kb  + (long)bh * 65536;
    const u16* vbh = vTb + (long)bh * 65536;   // [64 d][1024 s]

    // Q A-frags once, direct from global (rows 16w+nl, 16B aligned)
    const bfx8 aq0 = *(const bfx8*)(qbh + (l0 + 16 * w + nl) * 64 + quad * 8);
    const bfx8 aq1 = *(const bfx8*)(qbh + (l0 + 16 * w + nl) * 64 + quad * 8 + 32);

    f32x4 accv[4];
#pragma unroll
    for (int f = 0; f < 4; f++) accv[f] = (f32x4){0.f, 0.f, 0.f, 0.f};
    float zacc[4] = {0.f, 0.f, 0.f, 0.f};
    const int jb_base = l0 + 960;  // E-slice top row for r0=0

    for (int it = 0; it < 16; it++) {
        const int r0 = it * 64;
        __syncthreads();  // (A) prev iter's consumers done before restage

        // ---- stage K rows 16w..16w+15 (2 calls), VT same, E rows 32w..+31 (4)
        const int jb = jb_base - r0;
#pragma unroll
        for (int j = 0; j < 2; j++) {
            int row = 16 * w + 8 * j + rloc;
            gload16(kbh + (r0 + row) * 64 + cperm * 8, sK + (16 * w + 8 * j) * 64);
            gload16(vbh + row * 1024 + r0 + cperm * 8, sVT + (16 * w + 8 * j) * 64);
        }
#pragma unroll
        for (int j = 0; j < 4; j++) {
            int row = 32 * w + 8 * j + rloc;
            int je = jb + row; if (je > 2046) je = 2046;  // u=127 never read
            gload16(Eb + je * 64 + cperm * 8, sE + (32 * w + 8 * j) * 64);
        }
        // ---- prefetch prior & mask into regs (drained at barrier B, used after C)
        float pr[4][4], mval[4];
#pragma unroll
        for (int fn = 0; fn < 4; fn++) {
            mval[fn] = maskf[b * 1024 + r0 + fn * 16 + nl];
#pragma unroll
            for (int reg = 0; reg < 4; reg++) {
                long pidx = ((long)(bh * 1024 + l0 + 16 * w + 4 * quad + reg)) * 1024
                            + r0 + fn * 16 + nl;
                pr[fn][reg] = bf ? bf2f(((const u16*)prior)[pidx])
                                 : ((const float*)prior)[pidx];
            }
        }
        __syncthreads();  // (B) staged data visible

        // ---- band GEMMs: Dq -> regs (packed bf16), Dk -> LDS board (b64)
        const bfx8 ak0 = ld_sw(sK, 16 * w + nl, quad);
        const bfx8 ak1 = ld_sw(sK, 16 * w + nl, 4 + quad);
        u32 dqp[8][2];
#pragma unroll
        for (int fc = 0; fc < 8; fc++) {
            bfx8 be0 = ld_sw(sE, fc * 16 + nl, quad);
            bfx8 be1 = ld_sw(sE, fc * 16 + nl, 4 + quad);
            f32x4 dq = (f32x4){0.f, 0.f, 0.f, 0.f};
            dq = MFMA_BF16(aq0, be0, dq);
            dq = MFMA_BF16(aq1, be1, dq);
            f32x4 dk = (f32x4){0.f, 0.f, 0.f, 0.f};
            dk = MFMA_BF16(ak0, be0, dk);
            dk = MFMA_BF16(ak1, be1, dk);
            dqp[fc][0] = (u32)f2bf(dq[0]) | ((u32)f2bf(dq[1]) << 16);
            dqp[fc][1] = (u32)f2bf(dq[2]) | ((u32)f2bf(dq[3]) << 16);
            int u = fc * 16 + nl;  // board col-major [u][r], rows 16w+4quad+0..3
            u64 pk = (u64)f2bf(dk[0]) | ((u64)f2bf(dk[1]) << 16)
                   | ((u64)f2bf(dk[2]) << 32) | ((u64)f2bf(dk[3]) << 48);
            *(u64*)(sDk + u * 64 + (((4 * w + quad) ^ (u & 15)) * 4)) = pk;
        }
        // ---- QK^T for this wave's 16 rows x 64 cols
        f32x4 accs[4];
#pragma unroll
        for (int fn = 0; fn < 4; fn++) {
            bfx8 bk0 = ld_sw(sK, fn * 16 + nl, quad);
            bfx8 bk1 = ld_sw(sK, fn * 16 + nl, 4 + quad);
            f32x4 s = (f32x4){0.f, 0.f, 0.f, 0.f};
            s = MFMA_BF16(aq0, bk0, s);
            s = MFMA_BF16(aq1, bk1, s);
            accs[fn] = s;
        }
        __syncthreads();  // (C) Dk board visible; sE dead -> sP region free

        // ---- gather: Dq via ds_bpermute (same wave/quad/reg), Dk from board
#pragma unroll
        for (int reg = 0; reg < 4; reg++) {
            int srcl = quad * 16 + ((4 * quad + reg + 15 - nl) & 15);
            int bidx = srcl * 4;
            u32 bp[8];
#pragma unroll
            for (int fc = 0; fc < 8; fc++)
                bp[fc] = (u32)__builtin_amdgcn_ds_bpermute(bidx, (int)dqp[fc][reg >> 1]);
#pragma unroll
            for (int fn = 0; fn < 4; fn++) {
                int u = 16 * w + 4 * quad + reg + 63 - 16 * fn - nl;  // 0..126
                u32 word = bp[u >> 4];
                u16 dqv = (reg & 1) ? (u16)(word >> 16) : (u16)word;
                int ri = 16 * fn + nl;
                u16 dkv = sDk[u * 64 + (((ri >> 2) ^ (u & 15)) * 4) + (ri & 3)];
                float s = (accs[fn][reg] + bf2f(dqv) + bf2f(dkv)) * 0.125f + mval[fn];
                float e = __expf(s);  // logits ~ +-3: no max pass needed
                zacc[reg] += e;
                int li = 16 * w + 4 * quad + reg, ci = fn * 16 + nl;
                sP[li * 64 + (((ci >> 3) ^ (li & 7)) * 8) + (ci & 7)] =
                    f2bf(e * pr[fn][reg]);
            }
        }
        // sP rows 16w.. written and read by the SAME wave: no barrier needed
        bfx8 ap0 = ld_sw(sP, 16 * w + nl, quad);
        bfx8 ap1 = ld_sw(sP, 16 * w + nl, 4 + quad);
#pragma unroll
        for (int fd = 0; fd < 4; fd++) {
            bfx8 bv0 = ld_sw(sVT, fd * 16 + nl, quad);
            bfx8 bv1 = ld_sw(sVT, fd * 16 + nl, 4 + quad);
            accv[fd] = MFMA_BF16(ap0, bv0, accv[fd]);
            accv[fd] = MFMA_BF16(ap1, bv1, accv[fd]);
        }
    }

    // ---- finalize: reduce Z over the 16 col-lanes, scale, store
#pragma unroll
    for (int reg = 0; reg < 4; reg++) {
        float z = zacc[reg];
        z += __shfl_xor(z, 1);
        z += __shfl_xor(z, 2);
        z += __shfl_xor(z, 4);
        z += __shfl_xor(z, 8);
        zacc[reg] = z;
    }
    const float hm = hmf[h];
#pragma unroll
    for (int fd = 0; fd < 4; fd++) {
#pragma unroll
        for (int reg = 0; reg < 4; reg++) {
            int l = l0 + 16 * w + 4 * quad + reg;
            int d = fd * 16 + nl;
            float val = accv[fd][reg] * hm / zacc[reg];
            long oidx = ((long)(b * 1024 + l)) * 1024 + h * 64 + d;
            if (bf) ((u16*)out)[oidx] = f2bf(val);
            else    ((float*)out)[oidx] = val;
        }
    }
}

// ---------------------------------------------------------------------------
extern "C" void kernel_launch(void* const* d_in, const int* in_sizes, int n_in,
                              void* d_out, int out_size, void* d_ws, size_t ws_size,
                              hipStream_t stream) {
    // d_in: 0 hidden, 1 attention_mask, 2 prior, 3 head_mask,
    //       4 Wq, 5 bq, 6 Wk, 7 bk, 8 Wv, 9 bv, 10 dist_emb
    char* ws = (char*)d_ws;
    int*   flags   = (int*)ws;                  //       16 B (256 reserved)
    u16*   hid_bf  = (u16*)(ws + 256);          //  8388608 B
    u16*   wt_bf   = (u16*)(ws + 8388864);      //  6291456 B
    u16*   dist_bf = (u16*)(ws + 14680320);     //   262144 B
    float* mask_f  = (float*)(ws + 14942464);   //    16384 B
    float* bias_f  = (float*)(ws + 14958848);   //    12288 B
    float* hm_f    = (float*)(ws + 14971136);   //      256 B
    u16*   q_bf    = (u16*)(ws + 14971392);     //  8388608 B  [bh][s][d]
    u16*   k_bf    = (u16*)(ws + 23360000);     //  8388608 B  [bh][s][d]
    u16*   v_bf    = (u16*)(ws + 31748608);     //  8388608 B  [bh][d][s] (T)

    k_detect<<<1, 256, 0, stream>>>((const u32*)d_in[0], flags);
    k_prep<<<2048, 256, 0, stream>>>(d_in[0], d_in[10], d_in[1], d_in[3],
                                     d_in[5], d_in[7], d_in[9], flags,
                                     hid_bf, dist_bf, mask_f, hm_f, bias_f);
    k_transpose<<<dim3(32, 32, 3), dim3(32, 8), 0, stream>>>(
        d_in[4], d_in[6], d_in[8], flags, wt_bf);
    k_qkv_gemm<<<dim3(24, 32), 256, 0, stream>>>(hid_bf, wt_bf, bias_f,
                                                 q_bf, k_bf, v_bf);
    k_attn<<<dim3(64, 16), 256, 0, stream>>>(q_bf, k_bf, v_bf, dist_bf,
                                             mask_f, hm_f, d_in[2], flags, d_out);
}

// Round 3
// 521.875 us; speedup vs baseline: 1.0741x; 1.0741x over previous
//
#include <hip/hip_runtime.h>

// ---------------------------------------------------------------------------
// SelfAttentionModule: q/k/v proj + relative_key_query attention, MI355X.
// B=4, S=1024, D=1024, H=16, HD=64, MAXPOS=1024.
//
//   k_detect    : runtime input-dtype sniff (bf16 vs f32) -> flags[0]
//   k_prep      : normalize hidden/dist_emb -> bf16 ws; mask/bias/hm -> f32 ws
//   k_transpose : W[k][n] -> Wt[n][k] bf16
//   k_qkv_gemm  : 128x128 MFMA tile GEMM; q,k row-major [bh][s][d],
//                 v TRANSPOSED [bh][d][s]
//   k_attn      : fused attention. Bias boards stored as the 64x64 BIAS TILES
//                 (board_q[l][63-r], board_k[l][r]) -> linear immediate-offset
//                 LDS addressing, contiguous lane access, and 3/8 of band-fc
//                 tiles provably dead per wave (skipped MFMAs). 50176 B LDS
//                 (3 blocks/CU), 3 barriers/iter.
// ---------------------------------------------------------------------------

typedef unsigned short u16;
typedef unsigned int   u32;
typedef unsigned long long u64;
typedef __attribute__((ext_vector_type(8))) short bfx8;   // 8 bf16 = 4 VGPR
typedef __attribute__((ext_vector_type(4))) float f32x4;  // MFMA C/D

#define MFMA_BF16(a, b, c) __builtin_amdgcn_mfma_f32_16x16x32_bf16(a, b, c, 0, 0, 0)

__device__ __forceinline__ u16 f2bf(float f) {
    union { float f; u32 u; } c; c.f = f;
    u32 u = c.u;
    return (u16)((u + 0x7FFFu + ((u >> 16) & 1u)) >> 16);  // RNE
}
__device__ __forceinline__ float bf2f(u16 v) {
    union { u32 u; float f; } c; c.u = ((u32)v) << 16;
    return c.f;
}
__device__ __forceinline__ float load_f(const void* p, long i, bool bf) {
    return bf ? bf2f(((const u16*)p)[i]) : ((const float*)p)[i];
}
__device__ __forceinline__ u16 load_bf(const void* p, long i, bool bf) {
    return bf ? ((const u16*)p)[i] : f2bf(((const float*)p)[i]);
}

// async global->LDS, 16B/lane; LDS dest = wave-uniform base + lane*16
__device__ __forceinline__ void gload16(const u16* g, u16* l) {
    __builtin_amdgcn_global_load_lds(
        (__attribute__((address_space(1))) void*)g,
        (__attribute__((address_space(3))) void*)l, 16, 0, 0);
}

// swizzled b128 read: row pitch 64 u16 (8 chunks of 16B), chunk XOR (row&7)
__device__ __forceinline__ bfx8 ld_sw(const u16* arr, int row, int chunk) {
    return *(const bfx8*)(arr + row * 64 + ((chunk ^ (row & 7)) * 8));
}

// ---------------------------------------------------------------------------
__global__ void k_detect(const u32* hid, int* flags) {
    __shared__ int cnt;
    if (threadIdx.x == 0) cnt = 0;
    __syncthreads();
    int c = 0;
    for (int i = threadIdx.x; i < 1024; i += 256) {
        u32 w = hid[i];
        u32 e = (w >> 7) & 0xFFu;
        if (e >= 100u && e <= 140u) c++;
    }
    atomicAdd(&cnt, c);
    __syncthreads();
    if (threadIdx.x == 0) flags[0] = (cnt > 512) ? 1 : 0;
}

// ---------------------------------------------------------------------------
__global__ void k_prep(const void* hidden, const void* dist, const void* mask,
                       const void* hm, const void* bq, const void* bk,
                       const void* bv, const int* flags, u16* hid_bf,
                       u16* dist_bf, float* mask_f, float* hm_f, float* bias_f) {
    const bool bf = flags[0] != 0;
    const long NH = 4L * 1024 * 1024, ND = 2047L * 64, NM = 4096, NB = 3072, NHM = 16;
    const long TOT = NH + ND + NM + NB + NHM;
    for (long i = (long)blockIdx.x * 256 + threadIdx.x; i < TOT;
         i += (long)gridDim.x * 256) {
        if (i < NH) hid_bf[i] = load_bf(hidden, i, bf);
        else if (i < NH + ND) dist_bf[i - NH] = load_bf(dist, i - NH, bf);
        else if (i < NH + ND + NM) mask_f[i - NH - ND] = load_f(mask, i - NH - ND, bf);
        else if (i < NH + ND + NM + NB) {
            long j = i - NH - ND - NM;
            const void* src = (j < 1024) ? bq : ((j < 2048) ? bk : bv);
            bias_f[j] = load_f(src, j & 1023, bf);
        } else {
            long j = i - NH - ND - NM - NB;
            hm_f[j] = load_f(hm, j, bf);
        }
    }
}

// W[k][n] -> Wt[n][k] (bf16). grid (32,32,3), block (32,8)
__global__ void k_transpose(const void* Wq, const void* Wk, const void* Wv,
                            const int* flags, u16* wt) {
    const bool bf = flags[0] != 0;
    __shared__ float t[32][33];
    const int z = blockIdx.z;
    const void* W = (z == 0) ? Wq : ((z == 1) ? Wk : Wv);
    int x = blockIdx.x * 32 + threadIdx.x;  // n
    for (int i = 0; i < 4; i++) {
        int y = blockIdx.y * 32 + threadIdx.y + i * 8;  // k
        t[threadIdx.y + i * 8][threadIdx.x] = load_f(W, (long)y * 1024 + x, bf);
    }
    __syncthreads();
    int x2 = blockIdx.y * 32 + threadIdx.x;  // k
    u16* out = wt + (long)z * 1024 * 1024;
    for (int i = 0; i < 4; i++) {
        int y2 = blockIdx.x * 32 + threadIdx.y + i * 8;  // n
        out[(long)y2 * 1024 + x2] = f2bf(t[threadIdx.x][threadIdx.y + i * 8]);
    }
}

// ---------------------------------------------------------------------------
// QKV GEMM: C[m,n] = sum_k A[m,k]*Wt[n,k] + bias[n]; M=4096, N=3072, K=1024.
__global__ __launch_bounds__(256, 2)
void k_qkv_gemm(const u16* A, const u16* Bt, const float* bias,
                u16* qb, u16* kb, u16* vb) {
    __shared__ u16 sA[128 * 32];  // unpadded: required by global_load_lds
    __shared__ u16 sB[128 * 32];
    const int tid = threadIdx.x;
    const int w = tid >> 6, lane = tid & 63;
    const int quad = lane >> 4, nl = lane & 15;
    const int wr = w >> 1, wc = w & 1;
    const int n0 = blockIdx.x * 128, m0 = blockIdx.y * 128;

    f32x4 acc[4][4];
#pragma unroll
    for (int a = 0; a < 4; a++)
#pragma unroll
        for (int b = 0; b < 4; b++) acc[a][b] = (f32x4){0.f, 0.f, 0.f, 0.f};

    for (int kt = 0; kt < 32; kt++) {
        const int k0 = kt * 32;
        __syncthreads();
#pragma unroll
        for (int j = 0; j < 2; j++) {
            int row = 32 * w + 16 * j + (lane >> 2);
            int seg = lane & 3;
            gload16(A + (long)(m0 + row) * 1024 + k0 + seg * 8, sA + 1024 * w + 512 * j);
            gload16(Bt + (long)(n0 + row) * 1024 + k0 + seg * 8, sB + 1024 * w + 512 * j);
        }
        __syncthreads();

        bfx8 af[4], bfr[4];
#pragma unroll
        for (int f = 0; f < 4; f++) {
            af[f]  = *(const bfx8*)(sA + (64 * wr + 16 * f + nl) * 32 + quad * 8);
            bfr[f] = *(const bfx8*)(sB + (64 * wc + 16 * f + nl) * 32 + quad * 8);
        }
#pragma unroll
        for (int fm = 0; fm < 4; fm++)
#pragma unroll
            for (int fn = 0; fn < 4; fn++)
                acc[fm][fn] = MFMA_BF16(af[fm], bfr[fn], acc[fm][fn]);
    }

    // epilogue: +bias; q,k -> [bh][s][64]; v -> TRANSPOSED [bh][64][s]
#pragma unroll
    for (int fm = 0; fm < 4; fm++) {
#pragma unroll
        for (int fn = 0; fn < 4; fn++) {
            int n = n0 + 64 * wc + 16 * fn + nl;
            int which = n >> 10, hcol = n & 1023;
            int h = hcol >> 6, hd = hcol & 63;
            float bias_v = bias[n];
            int mbase = m0 + 64 * wr + 16 * fm + 4 * quad;
            int b = mbase >> 10, s = mbase & 1023;  // 4-reg group same row b
            if (which == 2) {
                u64 pk = 0;
#pragma unroll
                for (int reg = 0; reg < 4; reg++)
                    pk |= (u64)f2bf(acc[fm][fn][reg] + bias_v) << (16 * reg);
                *(u64*)&vb[((long)((b * 16 + h) * 64 + hd)) * 1024 + s] = pk;
            } else {
                u16* op = (which == 0) ? qb : kb;
#pragma unroll
                for (int reg = 0; reg < 4; reg++)
                    op[((long)((b * 16 + h) * 1024 + s + reg)) * 64 + hd] =
                        f2bf(acc[fm][fn][reg] + bias_v);
            }
        }
    }
}

// ---------------------------------------------------------------------------
// Fused attention. grid (B*H=64, S/64=16), 256 threads = 4 waves.
// Wave w owns score rows 16w..16w+15 of the 64-row l-tile.
//
// Bias boards ARE the bias tiles (shifted-diagonal storage):
//   board_q[l][t] = q[l].pe[l-r+63] with t = 63-r  (intra-wave)
//   board_k[l][r] = k[r].pe[l-r+63]                 (cross-wave)
// Producer validity t,row in [0,64) kills fc tiles outside a 5-tile window
// per wave -> band MFMA 32 -> 20 per iter.
__global__ __launch_bounds__(256, 3)
void k_attn(const u16* qb, const u16* kb, const u16* vTb, const u16* Eb,
            const float* maskf, const float* hmf, const void* prior,
            const int* flags, void* out) {
    __shared__ __align__(16) u16 smem[25088];  // 50176 B -> 3 blocks/CU
    u16* sK  = smem;            // [64 r][64 d]   swizzled (gload16)
    u16* sVT = smem + 4096;     // [64 d][64 r]   swizzled (gload16)
    u16* sE  = smem + 8192;     // [128 u][64 d]  swizzled (gload16)
    u16* sP  = smem + 8192;     // [64 l][72 r]   aliases sE (dead after band)
    u16* bqB = smem + 16384;    // [64 l][68 t]   bias board q
    u16* bkB = smem + 20736;    // [64 l][68 r]   bias board k

    const int tid = threadIdx.x;
    const int w = tid >> 6, lane = tid & 63;
    const int quad = lane >> 4, nl = lane & 15;
    const int rloc = lane >> 3;                   // row-within-8 for staging
    const int cperm = (lane & 7) ^ rloc;          // global chunk permutation
    const int bh = blockIdx.x, b = bh >> 4, h = bh & 15;
    const int l0 = blockIdx.y * 64;
    const bool bf = flags[0] != 0;

    const u16* qbh = qb  + (long)bh * 65536;
    const u16* kbh = kb  + (long)bh * 65536;
    const u16* vbh = vTb + (long)bh * 65536;   // [64 d][1024 s]

    // Q A-frags once, direct from global (rows 16w+nl, 16B aligned)
    const bfx8 aq0 = *(const bfx8*)(qbh + (l0 + 16 * w + nl) * 64 + quad * 8);
    const bfx8 aq1 = *(const bfx8*)(qbh + (l0 + 16 * w + nl) * 64 + quad * 8 + 32);

    f32x4 accv[4];
#pragma unroll
    for (int f = 0; f < 4; f++) accv[f] = (f32x4){0.f, 0.f, 0.f, 0.f};
    float zacc[4] = {0.f, 0.f, 0.f, 0.f};
    const int jb_base = l0 + 960;  // E-slice top row for r0=0

    // per-thread linear board bases (immediate offsets off these)
    const int lpb   = 16 * w + 4 * quad;            // row base (reg adds 1)
    const int bqrd  = lpb * 68 + 63 - nl;           // + reg*68 - fn*16
    const int bkrd  = lpb * 68 + nl;                // + reg*68 + fn*16

    for (int it = 0; it < 16; it++) {
        const int r0 = it * 64;
        __syncthreads();  // (A) prev iter's consumers done before restage

        // ---- stage K, V^T, E via async global->LDS (XOR chunk swizzle)
        const int jb = jb_base - r0;
#pragma unroll
        for (int j = 0; j < 2; j++) {
            int row = 16 * w + 8 * j + rloc;
            gload16(kbh + (r0 + row) * 64 + cperm * 8, sK + (16 * w + 8 * j) * 64);
            gload16(vbh + row * 1024 + r0 + cperm * 8, sVT + (16 * w + 8 * j) * 64);
        }
#pragma unroll
        for (int j = 0; j < 4; j++) {
            int row = 32 * w + 8 * j + rloc;
            int je = jb + row;
            if (je > 2046) je = 2046;   // only masked-off lanes consume these
            if (je < 0) je = 0;
            gload16(Eb + je * 64 + cperm * 8, sE + (32 * w + 8 * j) * 64);
        }
        // ---- prefetch prior & mask into regs (in flight during staging)
        float pr[4][4], mval[4];
#pragma unroll
        for (int fn = 0; fn < 4; fn++) {
            mval[fn] = maskf[b * 1024 + r0 + fn * 16 + nl];
#pragma unroll
            for (int reg = 0; reg < 4; reg++) {
                long pidx = ((long)(bh * 1024 + l0 + 16 * w + 4 * quad + reg)) * 1024
                            + r0 + fn * 16 + nl;
                pr[fn][reg] = bf ? bf2f(((const u16*)prior)[pidx])
                                 : ((const float*)prior)[pidx];
            }
        }
        __syncthreads();  // (B) staged data visible

        // ---- band GEMMs, only live fc windows; write bias boards (b16,
        //      contiguous lanes, exec-masked to the valid triangle)
        const bfx8 ak0 = ld_sw(sK, 16 * w + nl, quad);
        const bfx8 ak1 = ld_sw(sK, 16 * w + nl, 4 + quad);
#pragma unroll
        for (int d = 0; d < 5; d++) {
            const int fc = w + d;  // Dq live window [w, w+4]
            bfx8 be0 = ld_sw(sE, fc * 16 + nl, quad);
            bfx8 be1 = ld_sw(sE, fc * 16 + nl, 4 + quad);
            f32x4 dq = (f32x4){0.f, 0.f, 0.f, 0.f};
            dq = MFMA_BF16(aq0, be0, dq);
            dq = MFMA_BF16(aq1, be1, dq);
#pragma unroll
            for (int reg = 0; reg < 4; reg++) {
                int lp = lpb + reg;
                int t = 16 * fc + nl - lp;          // board_q col
                if (t >= 0 && t < 64) bqB[lp * 68 + t] = f2bf(dq[reg]);
            }
        }
#pragma unroll
        for (int d = 0; d < 5; d++) {
            const int fc = 3 - w + d;  // Dk live window [3-w, 7-w]
            bfx8 be0 = ld_sw(sE, fc * 16 + nl, quad);
            bfx8 be1 = ld_sw(sE, fc * 16 + nl, 4 + quad);
            f32x4 dk = (f32x4){0.f, 0.f, 0.f, 0.f};
            dk = MFMA_BF16(ak0, be0, dk);
            dk = MFMA_BF16(ak1, be1, dk);
#pragma unroll
            for (int reg = 0; reg < 4; reg++) {
                int rp = lpb + reg;                 // this wave's r row
                int row = 16 * fc + nl + rp - 63;   // board_k row = l
                if (row >= 0 && row < 64) bkB[row * 68 + rp] = f2bf(dk[reg]);
            }
        }
        // ---- QK^T for this wave's 16 rows x 64 cols
        f32x4 accs[4];
#pragma unroll
        for (int fn = 0; fn < 4; fn++) {
            bfx8 bk0 = ld_sw(sK, fn * 16 + nl, quad);
            bfx8 bk1 = ld_sw(sK, fn * 16 + nl, 4 + quad);
            f32x4 s = (f32x4){0.f, 0.f, 0.f, 0.f};
            s = MFMA_BF16(aq0, bk0, s);
            s = MFMA_BF16(aq1, bk1, s);
            accs[fn] = s;
        }
        __syncthreads();  // (C) boards visible; sE dead -> sP region free

        // ---- combine: 2 contiguous b16 reads/elem, exp, prior, sP write
#pragma unroll
        for (int fn = 0; fn < 4; fn++) {
#pragma unroll
            for (int reg = 0; reg < 4; reg++) {
                float dqv = bf2f(bqB[bqrd + reg * 68 - fn * 16]);
                float dkv = bf2f(bkB[bkrd + reg * 68 + fn * 16]);
                float s = (accs[fn][reg] + dqv + dkv) * 0.125f + mval[fn];
                float e = __expf(s);   // logits ~ +-3: no max pass needed
                zacc[reg] += e;
                sP[(lpb + reg) * 72 + fn * 16 + nl] = f2bf(e * pr[fn][reg]);
            }
        }
        // sP rows 16w.. written and read by the SAME wave: no barrier needed
        bfx8 ap0 = *(const bfx8*)(sP + (16 * w + nl) * 72 + quad * 8);
        bfx8 ap1 = *(const bfx8*)(sP + (16 * w + nl) * 72 + quad * 8 + 32);
#pragma unroll
        for (int fd = 0; fd < 4; fd++) {
            bfx8 bv0 = ld_sw(sVT, fd * 16 + nl, quad);
            bfx8 bv1 = ld_sw(sVT, fd * 16 + nl, 4 + quad);
            accv[fd] = MFMA_BF16(ap0, bv0, accv[fd]);
            accv[fd] = MFMA_BF16(ap1, bv1, accv[fd]);
        }
    }

    // ---- finalize: reduce Z over the 16 col-lanes, scale, store
#pragma unroll
    for (int reg = 0; reg < 4; reg++) {
        float z = zacc[reg];
        z += __shfl_xor(z, 1);
        z += __shfl_xor(z, 2);
        z += __shfl_xor(z, 4);
        z += __shfl_xor(z, 8);
        zacc[reg] = z;
    }
    const float hm = hmf[h];
#pragma unroll
    for (int fd = 0; fd < 4; fd++) {
#pragma unroll
        for (int reg = 0; reg < 4; reg++) {
            int l = l0 + 16 * w + 4 * quad + reg;
            int d = fd * 16 + nl;
            float val = accv[fd][reg] * hm / zacc[reg];
            long oidx = ((long)(b * 1024 + l)) * 1024 + h * 64 + d;
            if (bf) ((u16*)out)[oidx] = f2bf(val);
            else    ((float*)out)[oidx] = val;
        }
    }
}

// ---------------------------------------------------------------------------
extern "C" void kernel_launch(void* const* d_in, const int* in_sizes, int n_in,
                              void* d_out, int out_size, void* d_ws, size_t ws_size,
                              hipStream_t stream) {
    // d_in: 0 hidden, 1 attention_mask, 2 prior, 3 head_mask,
    //       4 Wq, 5 bq, 6 Wk, 7 bk, 8 Wv, 9 bv, 10 dist_emb
    char* ws = (char*)d_ws;
    int*   flags   = (int*)ws;                  //       16 B (256 reserved)
    u16*   hid_bf  = (u16*)(ws + 256);          //  8388608 B
    u16*   wt_bf   = (u16*)(ws + 8388864);      //  6291456 B
    u16*   dist_bf = (u16*)(ws + 14680320);     //   262144 B
    float* mask_f  = (float*)(ws + 14942464);   //    16384 B
    float* bias_f  = (float*)(ws + 14958848);   //    12288 B
    float* hm_f    = (float*)(ws + 14971136);   //      256 B
    u16*   q_bf    = (u16*)(ws + 14971392);     //  8388608 B  [bh][s][d]
    u16*   k_bf    = (u16*)(ws + 23360000);     //  8388608 B  [bh][s][d]
    u16*   v_bf    = (u16*)(ws + 31748608);     //  8388608 B  [bh][d][s] (T)

    k_detect<<<1, 256, 0, stream>>>((const u32*)d_in[0], flags);
    k_prep<<<2048, 256, 0, stream>>>(d_in[0], d_in[10], d_in[1], d_in[3],
                                     d_in[5], d_in[7], d_in[9], flags,
                                     hid_bf, dist_bf, mask_f, hm_f, bias_f);
    k_transpose<<<dim3(32, 32, 3), dim3(32, 8), 0, stream>>>(
        d_in[4], d_in[6], d_in[8], flags, wt_bf);
    k_qkv_gemm<<<dim3(24, 32), 256, 0, stream>>>(hid_bf, wt_bf, bias_f,
                                                 q_bf, k_bf, v_bf);
    k_attn<<<dim3(64, 16), 256, 0, stream>>>(q_bf, k_bf, v_bf, dist_bf,
                                             mask_f, hm_f, d_in[2], flags, d_out);
}